// Round 2
// baseline (376.639 us; speedup 1.0000x reference)
//
#include <hip/hip_runtime.h>
#include <math.h>

#define NN 20000
#define NE 320000
#define FIN 4
#define TP 12
#define OC 256
#define HIDN 128
#define OD 12
#define FT 48            // FIN*TP
#define NPB 8            // nodes per block in the fused kernel
#define LOG2E 1.44269504088896340736f

// workspace layout (float indices); XT last so we can drop it if ws is small
#define OFF_FLAG  0
#define OFF_DEG   64
#define OFF_DINV  (OFF_DEG + NN)
#define OFF_P     (OFF_DINV + NN)                 // [n][t][f] float4-grouped
#define OFF_MZ    (OFF_P + NN*FT)                 // pre-scaled by log2e
#define OFF_MH    (OFF_MZ + FIN*OC)               // pre-scaled by 2*log2e
#define OFF_CZ    (OFF_MH + FIN*OC)
#define OFF_CH    (OFF_CZ + OC)
#define OFF_PROBS (OFF_CH + OC)
#define OFF_W1T   (OFF_PROBS + 16)                // [j][k] 128x256
#define OFF_W2T   (OFF_W1T + OC*HIDN)             // [k][j] 12x128
#define OFF_XT    (OFF_W2T + HIDN*OD)             // [n][t][f] float4-grouped
#define NEED_XT_BYTES ((size_t)(OFF_XT + NN*FT) * 4)

// ---- detect whether edge_index arrived as int64 or int32 ----
__global__ void detect_kernel(const unsigned long long* ei, int* flag) {
    __shared__ int sbad;
    if (threadIdx.x == 0) sbad = 0;
    __syncthreads();
    int bad = 0;
    for (int i = threadIdx.x; i < 2048; i += 256) {
        unsigned long long v = ei[i];
        if (v >= (unsigned long long)NN) bad = 1;
    }
    if (bad) sbad = 1;
    __syncthreads();
    if (threadIdx.x == 0) *flag = (sbad == 0) ? 1 : 0;  // 1 => int64
}

__device__ __forceinline__ int load_idx(const void* ei, int is64, long off) {
    return is64 ? (int)((const long long*)ei)[off] : ((const int*)ei)[off];
}

// ---- weighted degree (edges + self loops) ----
__global__ void deg_kernel(const void* ei, const float* w, const int* flag, float* deg) {
    int i = blockIdx.x * blockDim.x + threadIdx.x;
    int is64 = *flag;
    if (i < NE) {
        int dst = load_idx(ei, is64, (long)NE + i);
        atomicAdd(&deg[dst], w[i]);
    } else {
        int n = i - NE;
        if (n < NN) atomicAdd(&deg[n], 1.0f);
    }
}

__global__ void dinv_kernel(const float* deg, float* dinv) {
    int i = blockIdx.x * blockDim.x + threadIdx.x;
    if (i < NN) {
        float d = deg[i];
        dinv[i] = d > 0.0f ? 1.0f / sqrtf(d) : 0.0f;
    }
}

// ---- transpose x to [n][t][f] (XT) and init P with self-loop contribution ----
__global__ void initP_kernel(const float* __restrict__ x, const float* __restrict__ dinv,
                             float4* __restrict__ P4, float4* __restrict__ XT4, int useXT) {
    int idx = blockIdx.x * blockDim.x + threadIdx.x;
    if (idx >= NN * TP) return;
    int n = idx / TP;
    int t = idx - n * TP;
    const float* xb = x + n * FT + t;
    float4 v = make_float4(xb[0], xb[12], xb[24], xb[36]);
    if (useXT) XT4[idx] = v;
    float di = dinv[n];
    float s = di * di;
    P4[idx] = make_float4(s * v.x, s * v.y, s * v.z, s * v.w);
}

// ---- edge scatter: thread per (edge, t); 4 features per thread ----
__global__ void scatter_kernel(const void* ei, const float* __restrict__ w, const int* flag,
                               const float* __restrict__ dinv, const float* __restrict__ x,
                               const float4* __restrict__ XT4, float* __restrict__ P, int useXT) {
    int idx = blockIdx.x * blockDim.x + threadIdx.x;
    if (idx >= NE * TP) return;
    int e = idx / TP;
    int t = idx - e * TP;
    int is64 = *flag;
    int src = load_idx(ei, is64, e);
    int dst = load_idx(ei, is64, (long)NE + e);
    float nrm = dinv[src] * w[e] * dinv[dst];
    float4 v;
    if (useXT) {
        v = XT4[src * TP + t];
    } else {
        const float* xb = x + src * FT + t;
        v = make_float4(xb[0], xb[12], xb[24], xb[36]);
    }
    float* pd = P + dst * FT + t * 4;
    atomicAdd(pd + 0, nrm * v.x);
    atomicAdd(pd + 1, nrm * v.y);
    atomicAdd(pd + 2, nrm * v.z);
    atomicAdd(pd + 3, nrm * v.w);
}

// ---- prep: fold weight chains (scaled for exp2), probs, W1T/W2T transposes ----
__global__ void prep_kernel(const float* __restrict__ Wz, const float* __restrict__ bz,
                            const float* __restrict__ Wh, const float* __restrict__ bh,
                            const float* __restrict__ Lzw, const float* __restrict__ Lzb,
                            const float* __restrict__ Lhw, const float* __restrict__ Lhb,
                            const float* __restrict__ att,
                            const float* __restrict__ W1, const float* __restrict__ W2,
                            float* __restrict__ Mz, float* __restrict__ Mh,
                            float* __restrict__ cz, float* __restrict__ ch,
                            float* __restrict__ probs,
                            float* __restrict__ W1T, float* __restrict__ W2T) {
    int b = blockIdx.x;
    int c = threadIdx.x;
    if (b == 0) {
        float az0 = 0, az1 = 0, az2 = 0, az3 = 0, abz = 0;
        float ah0 = 0, ah1 = 0, ah2 = 0, ah3 = 0, abh = 0;
        for (int k = 0; k < OC; ++k) {
            float lz = Lzw[k * OC + c];
            float lh = Lhw[k * OC + c];
            az0 += Wz[k] * lz;
            az1 += Wz[OC + k] * lz;
            az2 += Wz[2 * OC + k] * lz;
            az3 += Wz[3 * OC + k] * lz;
            abz += bz[k] * lz;
            ah0 += Wh[k] * lh;
            ah1 += Wh[OC + k] * lh;
            ah2 += Wh[2 * OC + k] * lh;
            ah3 += Wh[3 * OC + k] * lh;
            abh += bh[k] * lh;
        }
        const float sz = LOG2E, sh = 2.0f * LOG2E;
        Mz[c] = az0 * sz; Mz[OC + c] = az1 * sz; Mz[2 * OC + c] = az2 * sz; Mz[3 * OC + c] = az3 * sz;
        Mh[c] = ah0 * sh; Mh[OC + c] = ah1 * sh; Mh[2 * OC + c] = ah2 * sh; Mh[3 * OC + c] = ah3 * sh;
        cz[c] = (abz + Lzb[c]) * sz;
        ch[c] = (abh + Lhb[c]) * sh;
        if (c == 0) {
            float m = att[0];
            for (int t = 1; t < TP; ++t) m = fmaxf(m, att[t]);
            float s = 0.0f, e[TP];
            for (int t = 0; t < TP; ++t) { e[t] = expf(att[t] - m); s += e[t]; }
            for (int t = 0; t < TP; ++t) probs[t] = e[t] / s;
        }
    } else {
        int j = b - 1;                    // 0..127
        W1T[j * OC + c] = W1[c * HIDN + j];
        if (j < OD && c < HIDN) W2T[j * HIDN + c] = W2[c * OD + j];
    }
}

// ---- fused per-node: gated accumulation over T + output MLP ----
__global__ __launch_bounds__(256) void main_kernel(
    const float4* __restrict__ P4,
    const float* __restrict__ Mz, const float* __restrict__ Mh,
    const float* __restrict__ cz, const float* __restrict__ ch,
    const float* __restrict__ probs,
    const float* __restrict__ W1T, const float* __restrict__ b1,
    const float* __restrict__ W2T, const float* __restrict__ b2,
    float* __restrict__ out) {
    int c = threadIdx.x;
    int nb = blockIdx.x * NPB;
    __shared__ float4 shp4[NPB * TP];
    __shared__ float shh[NPB][OC];
    __shared__ float shh1[NPB][HIDN];

    if (c < NPB * TP) shp4[c] = P4[nb * TP + c];
    float mz0 = Mz[c], mz1 = Mz[OC + c], mz2 = Mz[2 * OC + c], mz3 = Mz[3 * OC + c];
    float mh0 = Mh[c], mh1 = Mh[OC + c], mh2 = Mh[2 * OC + c], mh3 = Mh[3 * OC + c];
    float czc = cz[c], chc = ch[c];
    __syncthreads();

    for (int m = 0; m < NPB; ++m) {
        float hacc = 0.0f;
#pragma unroll
        for (int t = 0; t < TP; ++t) {
            float4 p = shp4[m * TP + t];
            float az = czc + p.x * mz0 + p.y * mz1 + p.z * mz2 + p.w * mz3;   // pre-scaled log2e
            float ah = chc + p.x * mh0 + p.y * mh1 + p.z * mh2 + p.w * mh3;   // pre-scaled 2*log2e
            float ea = __builtin_exp2f(az);       // e^{az_orig}
            float eb = __builtin_exp2f(ah);       // e^{2*ah_orig}
            // (1-sigmoid(az))*tanh(ah) = (eb-1) / ((1+ea)*(1+eb)) — one rcp
            float den = (1.0f + ea) * (1.0f + eb);
            float num = probs[t] * (eb - 1.0f);
            float r = __builtin_amdgcn_rcpf(den);
            hacc = fmaf(num, r, hacc);
        }
        out[NN * OD + (nb + m) * OC + c] = hacc;    // out_hidden
        shh[m][c] = fmaxf(hacc, 0.0f);
    }
    __syncthreads();

    // layer 1: thread = (half: 4 nodes) x (j: 128 hidden); W1T rows are contiguous
    {
        int j = c & (HIDN - 1);
        int m0 = (c >> 7) * 4;
        const float4* w1r = (const float4*)&W1T[j * OC];
        const float4* h0r = (const float4*)&shh[m0 + 0][0];
        const float4* h1r = (const float4*)&shh[m0 + 1][0];
        const float4* h2r = (const float4*)&shh[m0 + 2][0];
        const float4* h3r = (const float4*)&shh[m0 + 3][0];
        float s0 = 0, s1 = 0, s2 = 0, s3 = 0;
        for (int k4 = 0; k4 < OC / 4; ++k4) {
            float4 w = w1r[k4];
            float4 a0 = h0r[k4], a1 = h1r[k4], a2 = h2r[k4], a3 = h3r[k4];
            s0 = fmaf(w.x, a0.x, fmaf(w.y, a0.y, fmaf(w.z, a0.z, fmaf(w.w, a0.w, s0))));
            s1 = fmaf(w.x, a1.x, fmaf(w.y, a1.y, fmaf(w.z, a1.z, fmaf(w.w, a1.w, s1))));
            s2 = fmaf(w.x, a2.x, fmaf(w.y, a2.y, fmaf(w.z, a2.z, fmaf(w.w, a2.w, s2))));
            s3 = fmaf(w.x, a3.x, fmaf(w.y, a3.y, fmaf(w.z, a3.z, fmaf(w.w, a3.w, s3))));
        }
        float bb = b1[j];
        shh1[m0 + 0][j] = fmaxf(s0 + bb, 0.0f);
        shh1[m0 + 1][j] = fmaxf(s1 + bb, 0.0f);
        shh1[m0 + 2][j] = fmaxf(s2 + bb, 0.0f);
        shh1[m0 + 3][j] = fmaxf(s3 + bb, 0.0f);
    }
    __syncthreads();

    // layer 2: 96 active threads = 8 nodes x 12 outputs; W2T rows contiguous
    if (c < NPB * OD) {
        int m = c / OD;
        int k = c - m * OD;
        const float4* w2r = (const float4*)&W2T[k * HIDN];
        const float4* hr  = (const float4*)&shh1[m][0];
        float a = b2[k];
        for (int j4 = 0; j4 < HIDN / 4; ++j4) {
            float4 w = w2r[j4];
            float4 h = hr[j4];
            a = fmaf(w.x, h.x, fmaf(w.y, h.y, fmaf(w.z, h.z, fmaf(w.w, h.w, a))));
        }
        out[(nb + m) * OD + k] = a;
    }
}

extern "C" void kernel_launch(void* const* d_in, const int* in_sizes, int n_in,
                              void* d_out, int out_size, void* d_ws, size_t ws_size,
                              hipStream_t stream) {
    const float* x   = (const float*)d_in[0];
    const void*  ei  = d_in[1];
    const float* ea  = (const float*)d_in[2];
    const float* att = (const float*)d_in[3];
    const float* Wz  = (const float*)d_in[4];
    const float* bz  = (const float*)d_in[5];
    // d_in[6], d_in[7] (Wr, br) dead: Hzero*R == 0 in the reference
    const float* Wh  = (const float*)d_in[8];
    const float* bh  = (const float*)d_in[9];
    const float* Lzw = (const float*)d_in[10];
    const float* Lzb = (const float*)d_in[11];
    // d_in[12], d_in[13] (Lrw, Lrb) dead
    const float* Lhw = (const float*)d_in[14];
    const float* Lhb = (const float*)d_in[15];
    const float* W1  = (const float*)d_in[16];
    const float* b1  = (const float*)d_in[17];
    const float* W2  = (const float*)d_in[18];
    const float* b2  = (const float*)d_in[19];

    float* out = (float*)d_out;
    float* ws  = (float*)d_ws;

    int*   flag  = (int*)(ws + OFF_FLAG);
    float* deg   = ws + OFF_DEG;
    float* dinv  = ws + OFF_DINV;
    float* P     = ws + OFF_P;
    float* Mz    = ws + OFF_MZ;
    float* Mh    = ws + OFF_MH;
    float* cz    = ws + OFF_CZ;
    float* ch    = ws + OFF_CH;
    float* probs = ws + OFF_PROBS;
    float* W1T   = ws + OFF_W1T;
    float* W2T   = ws + OFF_W2T;
    float* XT    = ws + OFF_XT;
    int useXT = (ws_size >= NEED_XT_BYTES) ? 1 : 0;

    detect_kernel<<<1, 256, 0, stream>>>((const unsigned long long*)ei, flag);
    hipMemsetAsync(deg, 0, NN * sizeof(float), stream);
    deg_kernel<<<(NE + NN + 255) / 256, 256, 0, stream>>>(ei, ea, flag, deg);
    dinv_kernel<<<(NN + 255) / 256, 256, 0, stream>>>(deg, dinv);
    initP_kernel<<<(NN * TP + 255) / 256, 256, 0, stream>>>(x, dinv, (float4*)P, (float4*)XT, useXT);
    scatter_kernel<<<(NE * TP + 255) / 256, 256, 0, stream>>>(ei, ea, flag, dinv, x,
                                                              (const float4*)XT, P, useXT);
    prep_kernel<<<1 + HIDN, 256, 0, stream>>>(Wz, bz, Wh, bh, Lzw, Lzb, Lhw, Lhb, att,
                                              W1, W2, Mz, Mh, cz, ch, probs, W1T, W2T);
    main_kernel<<<NN / NPB, 256, 0, stream>>>((const float4*)P, Mz, Mh, cz, ch, probs,
                                              W1T, b1, W2T, b2, out);
}

// Round 3
// 247.992 us; speedup vs baseline: 1.5188x; 1.5188x over previous
//
#include <hip/hip_runtime.h>
#include <math.h>

#define NN 20000
#define NE 320000
#define FIN 4
#define TP 12
#define OC 256
#define HIDN 128
#define OD 12
#define FT 48            // FIN*TP
#define NPB 16           // nodes per block in the fused kernel
#define LOG2E 1.44269504088896340736f

// ---- workspace layout (float indices) ----
#define OFF_FLAG  0
#define OFF_CNT   64                       // int[NN]
#define OFF_DEG   (OFF_CNT + NN)           // float[NN]  (cnt+deg zeroed by one memset)
#define OFF_POS   (OFF_DEG + NN)           // int[NN]
#define OFF_ROWS  (OFF_POS + NN)           // int[NN+1] (+pad)
#define OFF_DINV  (OFF_ROWS + NN + 32)     // float[NN]
#define OFF_MZ    (OFF_DINV + NN)          // float[4*OC], pre-scaled log2e
#define OFF_MH    (OFF_MZ + FIN*OC)        // float[4*OC], pre-scaled 2*log2e
#define OFF_CZ    (OFF_MH + FIN*OC)
#define OFF_CH    (OFF_CZ + OC)
#define OFF_PROBS (OFF_CH + OC)
#define OFF_W2T   (OFF_PROBS + 16)         // [k][j] 12x128
#define OFF_EREC  (OFF_W2T + HIDN*OD)      // float2[NE]: {src_as_float, nrm}
#define OFF_XT    (OFF_EREC + 2*NE)        // float4[NN*TP]: x transposed to [n][t][f]
#define NEED_XT_BYTES ((size_t)(OFF_XT + NN*FT) * 4)

// ---- detect whether edge_index arrived as int64 or int32 ----
__global__ void detect_kernel(const unsigned long long* ei, int* flag) {
    __shared__ int sbad;
    if (threadIdx.x == 0) sbad = 0;
    __syncthreads();
    int bad = 0;
    for (int i = threadIdx.x; i < 2048; i += 256) {
        unsigned long long v = ei[i];
        if (v >= (unsigned long long)NN) bad = 1;
    }
    if (bad) sbad = 1;
    __syncthreads();
    if (threadIdx.x == 0) *flag = (sbad == 0) ? 1 : 0;  // 1 => int64
}

__device__ __forceinline__ int load_idx(const void* ei, int is64, long off) {
    return is64 ? (int)((const long long*)ei)[off] : ((const int*)ei)[off];
}

// ---- count in-degree (int) and weighted degree (float) per dst ----
__global__ void count_kernel(const void* ei, const float* __restrict__ w, const int* flag,
                             int* __restrict__ cnt, float* __restrict__ deg) {
    int e = blockIdx.x * blockDim.x + threadIdx.x;
    if (e >= NE) return;
    int is64 = *flag;
    int dst = load_idx(ei, is64, (long)NE + e);
    atomicAdd(&cnt[dst], 1);
    atomicAdd(&deg[dst], w[e]);
}

// ---- single-block scan: rowstart/pos = exclusive prefix of cnt; dinv = rsqrt(deg+1) ----
#define SEG 20
__global__ __launch_bounds__(1024) void scan_kernel(const int* __restrict__ cnt,
                                                    const float* __restrict__ deg,
                                                    int* __restrict__ rowstart,
                                                    int* __restrict__ pos,
                                                    float* __restrict__ dinv) {
    __shared__ int sh[1024];
    int i = threadIdx.x;
    int base = i * SEG;
    int loc[SEG];
    int s = 0;
    for (int q = 0; q < SEG; ++q) {
        int n = base + q;
        int v = (n < NN) ? cnt[n] : 0;
        loc[q] = s;
        s += v;
    }
    sh[i] = s;
    __syncthreads();
    for (int off = 1; off < 1024; off <<= 1) {
        int v = (i >= off) ? sh[i - off] : 0;
        __syncthreads();
        sh[i] += v;
        __syncthreads();
    }
    int excl = (i == 0) ? 0 : sh[i - 1];
    for (int q = 0; q < SEG; ++q) {
        int n = base + q;
        if (n < NN) {
            int r = excl + loc[q];
            rowstart[n] = r;
            pos[n] = r;
            float d = deg[n] + 1.0f;            // + self-loop weight
            dinv[n] = 1.0f / sqrtf(d);
        }
    }
    if (i == 1023) rowstart[NN] = sh[1023];
}

// ---- transpose x to [n][t][f] float4 ----
__global__ void xt_kernel(const float* __restrict__ x, float4* __restrict__ XT4) {
    int idx = blockIdx.x * blockDim.x + threadIdx.x;
    if (idx >= NN * TP) return;
    int n = idx / TP;
    int t = idx - n * TP;
    const float* xb = x + n * FT + t;
    XT4[idx] = make_float4(xb[0], xb[12], xb[24], xb[36]);
}

// ---- fill CSR edge records {src, nrm} ----
__global__ void fill_kernel(const void* ei, const float* __restrict__ w, const int* flag,
                            const float* __restrict__ dinv, int* __restrict__ pos,
                            float2* __restrict__ erec) {
    int e = blockIdx.x * blockDim.x + threadIdx.x;
    if (e >= NE) return;
    int is64 = *flag;
    int src = load_idx(ei, is64, e);
    int dst = load_idx(ei, is64, (long)NE + e);
    float nrm = dinv[src] * w[e] * dinv[dst];
    int slot = atomicAdd(&pos[dst], 1);
    erec[slot] = make_float2(__int_as_float(src), nrm);
}

// ---- prep: fold weight chains (scaled for exp2), probs, W2T transpose ----
__global__ void prep_kernel(const float* __restrict__ Wz, const float* __restrict__ bz,
                            const float* __restrict__ Wh, const float* __restrict__ bh,
                            const float* __restrict__ Lzw, const float* __restrict__ Lzb,
                            const float* __restrict__ Lhw, const float* __restrict__ Lhb,
                            const float* __restrict__ att, const float* __restrict__ W2,
                            float* __restrict__ Mz, float* __restrict__ Mh,
                            float* __restrict__ cz, float* __restrict__ ch,
                            float* __restrict__ probs, float* __restrict__ W2T) {
    int c = threadIdx.x;
    if (blockIdx.x == 0) {
        float az0 = 0, az1 = 0, az2 = 0, az3 = 0, abz = 0;
        float ah0 = 0, ah1 = 0, ah2 = 0, ah3 = 0, abh = 0;
        for (int k = 0; k < OC; ++k) {
            float lz = Lzw[k * OC + c];
            float lh = Lhw[k * OC + c];
            az0 += Wz[k] * lz;
            az1 += Wz[OC + k] * lz;
            az2 += Wz[2 * OC + k] * lz;
            az3 += Wz[3 * OC + k] * lz;
            abz += bz[k] * lz;
            ah0 += Wh[k] * lh;
            ah1 += Wh[OC + k] * lh;
            ah2 += Wh[2 * OC + k] * lh;
            ah3 += Wh[3 * OC + k] * lh;
            abh += bh[k] * lh;
        }
        const float sz = LOG2E, sh2 = 2.0f * LOG2E;
        Mz[c] = az0 * sz; Mz[OC + c] = az1 * sz; Mz[2 * OC + c] = az2 * sz; Mz[3 * OC + c] = az3 * sz;
        Mh[c] = ah0 * sh2; Mh[OC + c] = ah1 * sh2; Mh[2 * OC + c] = ah2 * sh2; Mh[3 * OC + c] = ah3 * sh2;
        cz[c] = (abz + Lzb[c]) * sz;
        ch[c] = (abh + Lhb[c]) * sh2;
        if (c == 0) {
            float m = att[0];
            for (int t = 1; t < TP; ++t) m = fmaxf(m, att[t]);
            float s = 0.0f, e[TP];
            for (int t = 0; t < TP; ++t) { e[t] = expf(att[t] - m); s += e[t]; }
            for (int t = 0; t < TP; ++t) probs[t] = e[t] / s;
        }
    } else {
        if (c < HIDN)
            for (int k = 0; k < OD; ++k) W2T[k * HIDN + c] = W2[c * OD + k];
    }
}

// ---- fused: CSR gather (P tile) + gate accumulation + output MLP ----
__global__ __launch_bounds__(256) void main_kernel(
    const int* __restrict__ rowstart, const float2* __restrict__ erec,
    const float4* __restrict__ XT4, const float* __restrict__ x,
    const float* __restrict__ dinv, int useXT,
    const float* __restrict__ Mz, const float* __restrict__ Mh,
    const float* __restrict__ cz, const float* __restrict__ ch,
    const float* __restrict__ probs,
    const float* __restrict__ W1, const float* __restrict__ b1,
    const float* __restrict__ W2T, const float* __restrict__ b2,
    float* __restrict__ out) {
    int c = threadIdx.x;
    int nb = blockIdx.x * NPB;
    __shared__ float4 shp4[NPB * TP];          // 3 KB
    __shared__ float shh[NPB][OC];             // 16 KB
    __shared__ float shh1[NPB][HIDN + 4];      // 8.25 KB (pad kills layer-2 conflicts)

    // per-channel constants (registers; probs become SGPR-resident)
    float mz0 = Mz[c], mz1 = Mz[OC + c], mz2 = Mz[2 * OC + c], mz3 = Mz[3 * OC + c];
    float mh0 = Mh[c], mh1 = Mh[OC + c], mh2 = Mh[2 * OC + c], mh3 = Mh[3 * OC + c];
    float czc = cz[c], chc = ch[c];
    float pr[TP];
#pragma unroll
    for (int t = 0; t < TP; ++t) pr[t] = probs[t];

    // ---- gather phase: 192 threads own one (node, t) float4 row ----
    if (c < NPB * TP) {
        int m = c / TP;
        int t = c - m * TP;
        int n = nb + m;
        float dn = dinv[n];
        float4 xv;
        if (useXT) xv = XT4[n * TP + t];
        else { const float* xb = x + n * FT + t; xv = make_float4(xb[0], xb[12], xb[24], xb[36]); }
        float sw = dn * dn;                    // self-loop norm
        float4 acc = make_float4(sw * xv.x, sw * xv.y, sw * xv.z, sw * xv.w);
        int e0 = rowstart[n], e1 = rowstart[n + 1];
        for (int e = e0; e < e1; ++e) {
            float2 r = erec[e];
            int s = __float_as_int(r.x);
            float4 xs;
            if (useXT) xs = XT4[s * TP + t];
            else { const float* xb = x + s * FT + t; xs = make_float4(xb[0], xb[12], xb[24], xb[36]); }
            acc.x = fmaf(r.y, xs.x, acc.x);
            acc.y = fmaf(r.y, xs.y, acc.y);
            acc.z = fmaf(r.y, xs.z, acc.z);
            acc.w = fmaf(r.y, xs.w, acc.w);
        }
        shp4[c] = acc;
    }
    __syncthreads();

    // ---- gate phase: all shp4 reads are wave-uniform (broadcast, conflict-free) ----
    for (int m = 0; m < NPB; ++m) {
        float hacc = 0.0f;
#pragma unroll
        for (int t = 0; t < TP; ++t) {
            float4 p = shp4[m * TP + t];
            float az = czc + p.x * mz0 + p.y * mz1 + p.z * mz2 + p.w * mz3;  // *log2e
            float ah = chc + p.x * mh0 + p.y * mh1 + p.z * mh2 + p.w * mh3;  // *2log2e
            float ea = __builtin_exp2f(az);    // e^{az}
            float eb = __builtin_exp2f(ah);    // e^{2ah}
            // (1-sigmoid(az))*tanh(ah) = (eb-1)/((1+ea)(1+eb))
            float den = (1.0f + ea) * (1.0f + eb);
            float num = pr[t] * (eb - 1.0f);
            hacc = fmaf(num, __builtin_amdgcn_rcpf(den), hacc);
        }
        out[NN * OD + (nb + m) * OC + c] = hacc;   // out_hidden
        shh[m][c] = fmaxf(hacc, 0.0f);
    }
    __syncthreads();

    // ---- layer 1: thread = (half: 8 nodes) x (j: 128); W1 [k][j] coalesced, shh broadcast ----
    {
        int j = c & (HIDN - 1);
        int m0 = (c >> 7) * 8;
        float s0 = 0, s1 = 0, s2 = 0, s3 = 0, s4 = 0, s5 = 0, s6 = 0, s7 = 0;
        for (int k4 = 0; k4 < OC / 4; ++k4) {
            int kb = k4 * 4;
            float w0 = W1[(kb + 0) * HIDN + j];
            float w1 = W1[(kb + 1) * HIDN + j];
            float w2 = W1[(kb + 2) * HIDN + j];
            float w3 = W1[(kb + 3) * HIDN + j];
            float4 h0 = *(const float4*)&shh[m0 + 0][kb];
            float4 h1 = *(const float4*)&shh[m0 + 1][kb];
            float4 h2 = *(const float4*)&shh[m0 + 2][kb];
            float4 h3 = *(const float4*)&shh[m0 + 3][kb];
            float4 h4 = *(const float4*)&shh[m0 + 4][kb];
            float4 h5 = *(const float4*)&shh[m0 + 5][kb];
            float4 h6 = *(const float4*)&shh[m0 + 6][kb];
            float4 h7 = *(const float4*)&shh[m0 + 7][kb];
            s0 = fmaf(w0, h0.x, fmaf(w1, h0.y, fmaf(w2, h0.z, fmaf(w3, h0.w, s0))));
            s1 = fmaf(w0, h1.x, fmaf(w1, h1.y, fmaf(w2, h1.z, fmaf(w3, h1.w, s1))));
            s2 = fmaf(w0, h2.x, fmaf(w1, h2.y, fmaf(w2, h2.z, fmaf(w3, h2.w, s2))));
            s3 = fmaf(w0, h3.x, fmaf(w1, h3.y, fmaf(w2, h3.z, fmaf(w3, h3.w, s3))));
            s4 = fmaf(w0, h4.x, fmaf(w1, h4.y, fmaf(w2, h4.z, fmaf(w3, h4.w, s4))));
            s5 = fmaf(w0, h5.x, fmaf(w1, h5.y, fmaf(w2, h5.z, fmaf(w3, h5.w, s5))));
            s6 = fmaf(w0, h6.x, fmaf(w1, h6.y, fmaf(w2, h6.z, fmaf(w3, h6.w, s6))));
            s7 = fmaf(w0, h7.x, fmaf(w1, h7.y, fmaf(w2, h7.z, fmaf(w3, h7.w, s7))));
        }
        float bb = b1[j];
        shh1[m0 + 0][j] = fmaxf(s0 + bb, 0.0f);
        shh1[m0 + 1][j] = fmaxf(s1 + bb, 0.0f);
        shh1[m0 + 2][j] = fmaxf(s2 + bb, 0.0f);
        shh1[m0 + 3][j] = fmaxf(s3 + bb, 0.0f);
        shh1[m0 + 4][j] = fmaxf(s4 + bb, 0.0f);
        shh1[m0 + 5][j] = fmaxf(s5 + bb, 0.0f);
        shh1[m0 + 6][j] = fmaxf(s6 + bb, 0.0f);
        shh1[m0 + 7][j] = fmaxf(s7 + bb, 0.0f);
    }
    __syncthreads();

    // ---- layer 2: 192 threads = 16 nodes x 12 outputs ----
    if (c < NPB * OD) {
        int m = c / OD;
        int k = c - m * OD;
        const float4* w2r = (const float4*)&W2T[k * HIDN];
        const float4* hr  = (const float4*)&shh1[m][0];
        float a = b2[k];
        for (int j4 = 0; j4 < HIDN / 4; ++j4) {
            float4 w = w2r[j4];
            float4 h = hr[j4];
            a = fmaf(w.x, h.x, fmaf(w.y, h.y, fmaf(w.z, h.z, fmaf(w.w, h.w, a))));
        }
        out[(nb + m) * OD + k] = a;
    }
}

extern "C" void kernel_launch(void* const* d_in, const int* in_sizes, int n_in,
                              void* d_out, int out_size, void* d_ws, size_t ws_size,
                              hipStream_t stream) {
    const float* x   = (const float*)d_in[0];
    const void*  ei  = d_in[1];
    const float* ea  = (const float*)d_in[2];
    const float* att = (const float*)d_in[3];
    const float* Wz  = (const float*)d_in[4];
    const float* bz  = (const float*)d_in[5];
    // d_in[6], d_in[7] (Wr, br) dead: Hzero*R == 0 in the reference
    const float* Wh  = (const float*)d_in[8];
    const float* bh  = (const float*)d_in[9];
    const float* Lzw = (const float*)d_in[10];
    const float* Lzb = (const float*)d_in[11];
    // d_in[12], d_in[13] (Lrw, Lrb) dead
    const float* Lhw = (const float*)d_in[14];
    const float* Lhb = (const float*)d_in[15];
    const float* W1  = (const float*)d_in[16];
    const float* b1  = (const float*)d_in[17];
    const float* W2  = (const float*)d_in[18];
    const float* b2  = (const float*)d_in[19];

    float* out = (float*)d_out;
    float* ws  = (float*)d_ws;

    int*    flag     = (int*)(ws + OFF_FLAG);
    int*    cnt      = (int*)(ws + OFF_CNT);
    float*  deg      = ws + OFF_DEG;
    int*    pos      = (int*)(ws + OFF_POS);
    int*    rowstart = (int*)(ws + OFF_ROWS);
    float*  dinv     = ws + OFF_DINV;
    float*  Mz       = ws + OFF_MZ;
    float*  Mh       = ws + OFF_MH;
    float*  cz       = ws + OFF_CZ;
    float*  ch       = ws + OFF_CH;
    float*  probs    = ws + OFF_PROBS;
    float*  W2T      = ws + OFF_W2T;
    float2* erec     = (float2*)(ws + OFF_EREC);
    float*  XT       = ws + OFF_XT;
    int useXT = (ws_size >= NEED_XT_BYTES) ? 1 : 0;

    detect_kernel<<<1, 256, 0, stream>>>((const unsigned long long*)ei, flag);
    hipMemsetAsync(ws + OFF_CNT, 0, 2 * NN * sizeof(float), stream);   // cnt + deg
    count_kernel<<<(NE + 255) / 256, 256, 0, stream>>>(ei, ea, flag, cnt, deg);
    scan_kernel<<<1, 1024, 0, stream>>>(cnt, deg, rowstart, pos, dinv);
    if (useXT)
        xt_kernel<<<(NN * TP + 255) / 256, 256, 0, stream>>>(x, (float4*)XT);
    fill_kernel<<<(NE + 255) / 256, 256, 0, stream>>>(ei, ea, flag, dinv, pos, erec);
    prep_kernel<<<2, 256, 0, stream>>>(Wz, bz, Wh, bh, Lzw, Lzb, Lhw, Lhb, att, W2,
                                       Mz, Mh, cz, ch, probs, W2T);
    main_kernel<<<NN / NPB, 256, 0, stream>>>(rowstart, erec, (const float4*)XT, x, dinv,
                                              useXT, Mz, Mh, cz, ch, probs,
                                              W1, b1, W2T, b2, out);
}

// Round 4
// 186.580 us; speedup vs baseline: 2.0186x; 1.3291x over previous
//
#include <hip/hip_runtime.h>
#include <math.h>

#define NN 20000
#define NE 320000
#define FIN 4
#define TP 12
#define OC 256
#define HIDN 128
#define OD 12
#define FT 48            // FIN*TP
#define NPB 8            // nodes per block in the fused kernel
#define LOG2E 1.44269504088896340736f

#define NB_COUNT ((NE + 255) / 256)        // 1250
#define NB_XT    ((NN * TP + 255) / 256)   // 938
#define NB_SCAN  20                        // 1000 nodes per scan block

// ---- workspace layout (float indices) ----
#define OFF_CURSOR 0                        // int, atomic base cursor
#define OFF_CNT    64                       // int[NN]
#define OFF_DEG    (OFF_CNT + NN)           // float[NN]
#define OFF_POS    (OFF_DEG + NN)           // int[NN]
#define OFF_ROWS   (OFF_POS + NN)           // int[NN]
#define OFF_DINV   (OFF_ROWS + NN)          // float[NN]
#define OFF_MZ     (OFF_DINV + NN)          // float[4*OC], pre-scaled log2e
#define OFF_MH     (OFF_MZ + FIN*OC)        // float[4*OC], pre-scaled 2*log2e
#define OFF_CZ     (OFF_MH + FIN*OC)
#define OFF_CH     (OFF_CZ + OC)
#define OFF_PROBS  (OFF_CH + OC)
#define OFF_W2T    (OFF_PROBS + 16)         // [k][j] 12x128
#define OFF_EREC   (OFF_W2T + HIDN*OD)      // float2[NE]: {src_as_int, nrm}
#define OFF_XT     (OFF_EREC + 2*NE)        // float4[NN*TP]
#define NEED_XT_BYTES ((size_t)(OFF_XT + NN*FT) * 4)

// ---- per-wave int64/int32 detection: 2 instructions, no extra kernel ----
__device__ __forceinline__ int detect64(const void* ei) {
    const unsigned long long* p = (const unsigned long long*)ei;
    unsigned long long v = p[threadIdx.x & 63];
    // int64 indices: all values < NN. int32 data viewed as u64: hi word >0 a.s.
    return (__ballot(v < (unsigned long long)NN) == ~0ull) ? 1 : 0;
}

__device__ __forceinline__ int load_idx(const void* ei, int is64, long off) {
    return is64 ? (int)((const long long*)ei)[off] : ((const int*)ei)[off];
}

// ---- K1: count in-degree + weighted degree; extra blocks transpose x -> XT ----
__global__ __launch_bounds__(256) void build_kernel(
    const void* ei, const float* __restrict__ w, const float* __restrict__ x,
    int* __restrict__ cnt, float* __restrict__ deg, float4* __restrict__ XT4, int useXT) {
    int bid = blockIdx.x;
    if (bid < NB_COUNT) {
        int is64 = detect64(ei);
        int e = bid * 256 + threadIdx.x;
        if (e < NE) {
            int dst = load_idx(ei, is64, (long)NE + e);
            atomicAdd(&cnt[dst], 1);
            atomicAdd(&deg[dst], w[e]);
        }
    } else if (useXT) {
        int idx = (bid - NB_COUNT) * 256 + threadIdx.x;
        if (idx < NN * TP) {
            int n = idx / TP;
            int t = idx - n * TP;
            const float* xb = x + n * FT + t;
            XT4[idx] = make_float4(xb[0], xb[12], xb[24], xb[36]);
        }
    }
}

// ---- K2: blocks 0..19 = local scan + atomic base; block 20 = weight fold; 21 = W2T ----
__global__ __launch_bounds__(256) void scanprep_kernel(
    const int* __restrict__ cnt, const float* __restrict__ deg, int* __restrict__ cursor,
    int* __restrict__ rowstart, int* __restrict__ pos, float* __restrict__ dinv,
    const float* __restrict__ Wz, const float* __restrict__ bz,
    const float* __restrict__ Wh, const float* __restrict__ bh,
    const float* __restrict__ Lzw, const float* __restrict__ Lzb,
    const float* __restrict__ Lhw, const float* __restrict__ Lhb,
    const float* __restrict__ att, const float* __restrict__ W2,
    float* __restrict__ Mz, float* __restrict__ Mh,
    float* __restrict__ cz, float* __restrict__ ch,
    float* __restrict__ probs, float* __restrict__ W2T) {
    __shared__ int sh[256];
    __shared__ int shbase;
    int bid = blockIdx.x;
    int tid = threadIdx.x;
    if (bid < NB_SCAN) {
        int base = bid * 1000;
        int n0 = base + tid * 4;
        int loc[4];
        int s = 0;
#pragma unroll
        for (int q = 0; q < 4; ++q) {
            int n = n0 + q;
            int v = (n < base + 1000) ? cnt[n] : 0;
            loc[q] = s;
            s += v;
        }
        sh[tid] = s;
        __syncthreads();
        for (int off = 1; off < 256; off <<= 1) {
            int v = (tid >= off) ? sh[tid - off] : 0;
            __syncthreads();
            sh[tid] += v;
            __syncthreads();
        }
        if (tid == 0) shbase = atomicAdd(cursor, sh[255]);
        __syncthreads();
        int excl = shbase + (tid ? sh[tid - 1] : 0);
#pragma unroll
        for (int q = 0; q < 4; ++q) {
            int n = n0 + q;
            if (n < base + 1000) {
                int r = excl + loc[q];
                rowstart[n] = r;
                pos[n] = r;
                dinv[n] = 1.0f / sqrtf(deg[n] + 1.0f);   // + self-loop weight
            }
        }
    } else if (bid == NB_SCAN) {
        int c = tid;
        float az0 = 0, az1 = 0, az2 = 0, az3 = 0, abz = 0;
        float ah0 = 0, ah1 = 0, ah2 = 0, ah3 = 0, abh = 0;
        for (int k = 0; k < OC; ++k) {
            float lz = Lzw[k * OC + c];
            float lh = Lhw[k * OC + c];
            az0 += Wz[k] * lz;
            az1 += Wz[OC + k] * lz;
            az2 += Wz[2 * OC + k] * lz;
            az3 += Wz[3 * OC + k] * lz;
            abz += bz[k] * lz;
            ah0 += Wh[k] * lh;
            ah1 += Wh[OC + k] * lh;
            ah2 += Wh[2 * OC + k] * lh;
            ah3 += Wh[3 * OC + k] * lh;
            abh += bh[k] * lh;
        }
        const float sz = LOG2E, sh2 = 2.0f * LOG2E;
        Mz[c] = az0 * sz; Mz[OC + c] = az1 * sz; Mz[2 * OC + c] = az2 * sz; Mz[3 * OC + c] = az3 * sz;
        Mh[c] = ah0 * sh2; Mh[OC + c] = ah1 * sh2; Mh[2 * OC + c] = ah2 * sh2; Mh[3 * OC + c] = ah3 * sh2;
        cz[c] = (abz + Lzb[c]) * sz;
        ch[c] = (abh + Lhb[c]) * sh2;
        if (c == 0) {
            float m = att[0];
            for (int t = 1; t < TP; ++t) m = fmaxf(m, att[t]);
            float sum = 0.0f, e[TP];
            for (int t = 0; t < TP; ++t) { e[t] = expf(att[t] - m); sum += e[t]; }
            for (int t = 0; t < TP; ++t) probs[t] = e[t] / sum;
        }
    } else {
        if (tid < HIDN)
            for (int k = 0; k < OD; ++k) W2T[k * HIDN + tid] = W2[tid * OD + k];
    }
}

// ---- K3: fill CSR edge records {src, nrm} ----
__global__ __launch_bounds__(256) void fill_kernel(
    const void* ei, const float* __restrict__ w,
    const float* __restrict__ dinv, int* __restrict__ pos, float2* __restrict__ erec) {
    int is64 = detect64(ei);
    int e = blockIdx.x * 256 + threadIdx.x;
    if (e >= NE) return;
    int src = load_idx(ei, is64, e);
    int dst = load_idx(ei, is64, (long)NE + e);
    float nrm = dinv[src] * w[e] * dinv[dst];
    int slot = atomicAdd(&pos[dst], 1);
    erec[slot] = make_float2(__int_as_float(src), nrm);
}

// ---- K4: fused gather + gate accumulation + output MLP ----
__global__ __launch_bounds__(256) void main_kernel(
    const int* __restrict__ rowstart, const int* __restrict__ pos,
    const float2* __restrict__ erec,
    const float4* __restrict__ XT4, const float* __restrict__ x,
    const float* __restrict__ dinv, int useXT,
    const float* __restrict__ Mz, const float* __restrict__ Mh,
    const float* __restrict__ cz, const float* __restrict__ ch,
    const float* __restrict__ probs,
    const float* __restrict__ W1, const float* __restrict__ b1,
    const float* __restrict__ W2T, const float* __restrict__ b2,
    float* __restrict__ out) {
    int c = threadIdx.x;
    int nb = blockIdx.x * NPB;
    __shared__ float4 shp4[NPB * TP];          // 1.5 KB
    __shared__ float shh[NPB][OC];             // 8 KB (aliased as gather partials first)
    __shared__ float shh1[NPB][HIDN + 4];      // 4.1 KB

    float mz0 = Mz[c], mz1 = Mz[OC + c], mz2 = Mz[2 * OC + c], mz3 = Mz[3 * OC + c];
    float mh0 = Mh[c], mh1 = Mh[OC + c], mh2 = Mh[2 * OC + c], mh3 = Mh[3 * OC + c];
    float czc = cz[c], chc = ch[c];
    float pr[TP];
#pragma unroll
    for (int t = 0; t < TP; ++t) pr[t] = probs[t];

    // ---- gather: 192 threads, 2 per (node,t) row, each takes alternate edges ----
    float4* part = (float4*)&shh[0][0];        // 192*16B = 3KB inside shh's 8KB
    if (c < 2 * NPB * TP) {
        int q = c & 1;
        int i = c >> 1;                        // 0..95
        int m = i / TP;
        int t = i - m * TP;
        int n = nb + m;
        float4 acc = make_float4(0.f, 0.f, 0.f, 0.f);
        if (q == 0) {
            float dn = dinv[n];
            float sw = dn * dn;                // self-loop norm
            float4 xv;
            if (useXT) xv = XT4[n * TP + t];
            else { const float* xb = x + n * FT + t; xv = make_float4(xb[0], xb[12], xb[24], xb[36]); }
            acc = make_float4(sw * xv.x, sw * xv.y, sw * xv.z, sw * xv.w);
        }
        int e0 = rowstart[n], e1 = pos[n];
        for (int e = e0 + q; e < e1; e += 2) {
            float2 r = erec[e];
            int s = __float_as_int(r.x);
            float4 xs;
            if (useXT) xs = XT4[s * TP + t];
            else { const float* xb = x + s * FT + t; xs = make_float4(xb[0], xb[12], xb[24], xb[36]); }
            acc.x = fmaf(r.y, xs.x, acc.x);
            acc.y = fmaf(r.y, xs.y, acc.y);
            acc.z = fmaf(r.y, xs.z, acc.z);
            acc.w = fmaf(r.y, xs.w, acc.w);
        }
        part[c] = acc;
    }
    __syncthreads();
    if (c < NPB * TP) {
        float4 a = part[2 * c], b = part[2 * c + 1];
        shp4[c] = make_float4(a.x + b.x, a.y + b.y, a.z + b.z, a.w + b.w);
    }
    __syncthreads();

    // ---- gate phase (shp4 reads are wave-uniform broadcasts) ----
    for (int m = 0; m < NPB; ++m) {
        float hacc = 0.0f;
#pragma unroll
        for (int t = 0; t < TP; ++t) {
            float4 p = shp4[m * TP + t];
            float az = czc + p.x * mz0 + p.y * mz1 + p.z * mz2 + p.w * mz3;  // *log2e
            float ah = chc + p.x * mh0 + p.y * mh1 + p.z * mh2 + p.w * mh3;  // *2log2e
            float ea = __builtin_exp2f(az);    // e^{az}
            float eb = __builtin_exp2f(ah);    // e^{2ah}
            // (1-sigmoid(az))*tanh(ah) = (eb-1)/((1+ea)(1+eb))
            float den = (1.0f + ea) * (1.0f + eb);
            float num = pr[t] * (eb - 1.0f);
            hacc = fmaf(num, __builtin_amdgcn_rcpf(den), hacc);
        }
        out[NN * OD + (nb + m) * OC + c] = hacc;   // out_hidden
        shh[m][c] = fmaxf(hacc, 0.0f);
    }
    __syncthreads();

    // ---- layer 1: thread = (half: 4 nodes) x (j: 128); W1 coalesced, shh broadcast ----
    {
        int j = c & (HIDN - 1);
        int m0 = (c >> 7) * 4;
        float s0 = 0, s1 = 0, s2 = 0, s3 = 0;
        for (int k4 = 0; k4 < OC / 4; ++k4) {
            int kb = k4 * 4;
            float w0 = W1[(kb + 0) * HIDN + j];
            float w1 = W1[(kb + 1) * HIDN + j];
            float w2 = W1[(kb + 2) * HIDN + j];
            float w3 = W1[(kb + 3) * HIDN + j];
            float4 h0 = *(const float4*)&shh[m0 + 0][kb];
            float4 h1 = *(const float4*)&shh[m0 + 1][kb];
            float4 h2 = *(const float4*)&shh[m0 + 2][kb];
            float4 h3 = *(const float4*)&shh[m0 + 3][kb];
            s0 = fmaf(w0, h0.x, fmaf(w1, h0.y, fmaf(w2, h0.z, fmaf(w3, h0.w, s0))));
            s1 = fmaf(w0, h1.x, fmaf(w1, h1.y, fmaf(w2, h1.z, fmaf(w3, h1.w, s1))));
            s2 = fmaf(w0, h2.x, fmaf(w1, h2.y, fmaf(w2, h2.z, fmaf(w3, h2.w, s2))));
            s3 = fmaf(w0, h3.x, fmaf(w1, h3.y, fmaf(w2, h3.z, fmaf(w3, h3.w, s3))));
        }
        float bb = b1[j];
        shh1[m0 + 0][j] = fmaxf(s0 + bb, 0.0f);
        shh1[m0 + 1][j] = fmaxf(s1 + bb, 0.0f);
        shh1[m0 + 2][j] = fmaxf(s2 + bb, 0.0f);
        shh1[m0 + 3][j] = fmaxf(s3 + bb, 0.0f);
    }
    __syncthreads();

    // ---- layer 2: 96 threads = 8 nodes x 12 outputs ----
    if (c < NPB * OD) {
        int m = c / OD;
        int k = c - m * OD;
        const float4* w2r = (const float4*)&W2T[k * HIDN];
        const float4* hr  = (const float4*)&shh1[m][0];
        float a = b2[k];
        for (int j4 = 0; j4 < HIDN / 4; ++j4) {
            float4 w = w2r[j4];
            float4 h = hr[j4];
            a = fmaf(w.x, h.x, fmaf(w.y, h.y, fmaf(w.z, h.z, fmaf(w.w, h.w, a))));
        }
        out[(nb + m) * OD + k] = a;
    }
}

extern "C" void kernel_launch(void* const* d_in, const int* in_sizes, int n_in,
                              void* d_out, int out_size, void* d_ws, size_t ws_size,
                              hipStream_t stream) {
    const float* x   = (const float*)d_in[0];
    const void*  ei  = d_in[1];
    const float* ea  = (const float*)d_in[2];
    const float* att = (const float*)d_in[3];
    const float* Wz  = (const float*)d_in[4];
    const float* bz  = (const float*)d_in[5];
    // d_in[6], d_in[7] (Wr, br) dead: Hzero*R == 0 in the reference
    const float* Wh  = (const float*)d_in[8];
    const float* bh  = (const float*)d_in[9];
    const float* Lzw = (const float*)d_in[10];
    const float* Lzb = (const float*)d_in[11];
    // d_in[12], d_in[13] (Lrw, Lrb) dead
    const float* Lhw = (const float*)d_in[14];
    const float* Lhb = (const float*)d_in[15];
    const float* W1  = (const float*)d_in[16];
    const float* b1  = (const float*)d_in[17];
    const float* W2  = (const float*)d_in[18];
    const float* b2  = (const float*)d_in[19];

    float* out = (float*)d_out;
    float* ws  = (float*)d_ws;

    int*    cursor   = (int*)(ws + OFF_CURSOR);
    int*    cnt      = (int*)(ws + OFF_CNT);
    float*  deg      = ws + OFF_DEG;
    int*    pos      = (int*)(ws + OFF_POS);
    int*    rowstart = (int*)(ws + OFF_ROWS);
    float*  dinv     = ws + OFF_DINV;
    float*  Mz       = ws + OFF_MZ;
    float*  Mh       = ws + OFF_MH;
    float*  cz       = ws + OFF_CZ;
    float*  ch       = ws + OFF_CH;
    float*  probs    = ws + OFF_PROBS;
    float*  W2T      = ws + OFF_W2T;
    float2* erec     = (float2*)(ws + OFF_EREC);
    float*  XT       = ws + OFF_XT;
    int useXT = (ws_size >= NEED_XT_BYTES) ? 1 : 0;

    // zero cursor + cnt + deg in one memset
    hipMemsetAsync(ws, 0, (size_t)(OFF_DEG + NN) * sizeof(float), stream);
    build_kernel<<<NB_COUNT + NB_XT, 256, 0, stream>>>(ei, ea, x, cnt, deg, (float4*)XT, useXT);
    scanprep_kernel<<<NB_SCAN + 2, 256, 0, stream>>>(cnt, deg, cursor, rowstart, pos, dinv,
                                                     Wz, bz, Wh, bh, Lzw, Lzb, Lhw, Lhb,
                                                     att, W2, Mz, Mh, cz, ch, probs, W2T);
    fill_kernel<<<NB_COUNT, 256, 0, stream>>>(ei, ea, dinv, pos, erec);
    main_kernel<<<NN / NPB, 256, 0, stream>>>(rowstart, pos, erec, (const float4*)XT, x, dinv,
                                              useXT, Mz, Mh, cz, ch, probs,
                                              W1, b1, W2T, b2, out);
}